// Round 6
// baseline (885.671 us; speedup 1.0000x reference)
//
#include <hip/hip_runtime.h>
#include <cstdint>

#define NB 32
#define NN 1000
#define NC 1601
#define HID 64
#define ROWS (NB*NN)       // 32000
#define CAPB 4096          // candidate cap per batch (pass2 appends ~100-300)
#define NBIN 4096          // 12-bit key-prefix histogram
#define MSTR 40            // x-plane row stride (ushorts): 80 B rows, 16B aligned
#define HSTR 72            // h-plane row stride (ushorts)
#define PLSZ ((size_t)ROWS*64)   // one bf16 plane (ushorts)

typedef short short8 __attribute__((ext_vector_type(8)));
typedef float floatx4 __attribute__((ext_vector_type(4)));

__device__ __forceinline__ uint32_t f2key(float f){
  uint32_t u = __float_as_uint(f);
  return (u & 0x80000000u) ? ~u : (u | 0x80000000u);   // monotone float->uint
}
__device__ __forceinline__ float key2f(uint32_t k){
  uint32_t u = (k & 0x80000000u) ? (k & 0x7fffffffu) : ~k;
  return __uint_as_float(u);
}

// Dekker 3-way bf16 split: v ~= b0 + b1 + b2, residual ~2^-32 rel.
__device__ __forceinline__ void split3(float v, ushort& h0, ushort& h1, ushort& h2){
  uint32_t u0 = __float_as_uint(v) & 0xffff0000u;
  h0 = (ushort)(u0 >> 16);
  float r1 = v - __uint_as_float(u0);
  uint32_t u1 = __float_as_uint(r1) & 0xffff0000u;
  h1 = (ushort)(u1 >> 16);
  float r2 = r1 - __uint_as_float(u1);
  h2 = (ushort)(__float_as_uint(r2) >> 16);
}

// 6-term cross-product MFMA: (A0+A1+A2)(B0+B1+B2) to fp32-class accuracy.
#define MFMA6(acc, A0,A1,A2, B0,B1,B2) do { \
  acc = __builtin_amdgcn_mfma_f32_16x16x32_bf16(A0,B0,acc,0,0,0); \
  acc = __builtin_amdgcn_mfma_f32_16x16x32_bf16(A0,B1,acc,0,0,0); \
  acc = __builtin_amdgcn_mfma_f32_16x16x32_bf16(A1,B0,acc,0,0,0); \
  acc = __builtin_amdgcn_mfma_f32_16x16x32_bf16(A1,B1,acc,0,0,0); \
  acc = __builtin_amdgcn_mfma_f32_16x16x32_bf16(A2,B0,acc,0,0,0); \
  acc = __builtin_amdgcn_mfma_f32_16x16x32_bf16(A0,B2,acc,0,0,0); } while(0)

// ---------------------------------------------------------------------------
// Prep: split W1 (pad K to 1632) and W2 per head into 3 bf16 planes, laid out
// [head*3+plane][kstep][n(64)][k(32)] so fragment loads are coalesced.
// ---------------------------------------------------------------------------
__global__ __launch_bounds__(256, 1) void prep_w(
    const float* __restrict__ Ws1, const float* __restrict__ Wo1,
    const float* __restrict__ Ws2, const float* __restrict__ Wo2,
    ushort* __restrict__ w1s, ushort* __restrict__ w2s)
{
  int idx = blockIdx.x*256 + threadIdx.x;
  if (idx < 2*51*2048){
    int head = idx / (51*2048);
    int rem  = idx % (51*2048);
    int step = rem >> 11;
    int n    = (rem >> 5) & 63;
    int k    = rem & 31;
    int kg   = step*32 + k;
    const float* W = head ? Wo1 : Ws1;
    float v = (kg < NC) ? W[(size_t)kg*HID + n] : 0.f;
    ushort h0,h1,h2; split3(v,h0,h1,h2);
    size_t base = (size_t)head*3*104448 + rem;   // slice stride 51*2048
    w1s[base]            = h0;
    w1s[base + 104448]   = h1;
    w1s[base + 2*104448] = h2;
  } else {
    int idx2 = idx - 2*51*2048;
    if (idx2 < 2*4096){
      int head = idx2 >> 12;
      int rem  = idx2 & 4095;
      const float* W = head ? Wo2 : Ws2;
      int step = rem >> 11, n = (rem >> 5) & 63, k = rem & 31;
      float v = W[(size_t)(step*32 + k)*HID + n];
      ushort h0,h1,h2; split3(v,h0,h1,h2);
      size_t base = (size_t)head*3*4096 + rem;
      w2s[base]          = h0;
      w2s[base + 4096]   = h1;
      w2s[base + 2*4096] = h2;
    }
  }
}

// ---------------------------------------------------------------------------
// Kernel A: fused 2-layer MLP on matrix cores (bf16x3, 6-term), m97-style:
// ALL fragments come from LDS (ds_read_b128), W1 k-chunks staged cooperatively
// through registers (prefetched during compute), 2-barrier K-loop. R4/R5
// spilled ~750 MB scratch from 24 global-loaded B-fragments; LDS path keeps
// ~60 live VGPRs + 32 AGPR acc.
// LDS: xpl 3 planes x 64row x MSTR(40) = 15360 B; wch 6 slices x 2560 = 30720 B.
// ---------------------------------------------------------------------------
__global__ __launch_bounds__(256) void mlp_mfma(
    const float* __restrict__ x,
    const ushort* __restrict__ w1s, const ushort* __restrict__ w2s,
    const float* __restrict__ bs1, const float* __restrict__ bs2,
    const float* __restrict__ bo1, const float* __restrict__ bo2,
    ushort* __restrict__ sPl, ushort* __restrict__ oPl)
{
  __shared__ __align__(16) ushort smem[23040];   // 46080 B
  ushort* xpl = smem;            // [p][row*MSTR + k], p stride 2560
  ushort* wch = smem + 7680;     // [slice][nt*640 + col*40 + quad*8], slice stride 2560

  const int tid  = threadIdx.x;
  const int lane = tid & 63;
  const int wave = tid >> 6;
  const int col  = lane & 15;
  const int quad = lane >> 4;
  const int row0 = blockIdx.x * 64;

  const int wnt  = tid >> 6;           // staging decomposition of tid*8 elems
  const int wcol = (tid >> 2) & 15;
  const int wqd  = tid & 3;
  const int wdst = wnt*640 + wcol*40 + wqd*8;

  floatx4 acc[2][4];
  #pragma unroll
  for (int h=0; h<2; h++)
    #pragma unroll
    for (int nt=0; nt<4; nt++) acc[h][nt] = (floatx4){0.f,0.f,0.f,0.f};

  float stgx[8];
  uint4 stgw[6];
  #pragma unroll
  for (int it=0; it<8; it++){
    int u = tid + it*256;
    stgx[it] = x[(size_t)(row0 + (u>>5))*NC + (u&31)];
  }
  #pragma unroll
  for (int i=0; i<6; i++)
    stgw[i] = *(const uint4*)(w1s + (size_t)(i*51)*2048 + tid*8);

  for (int s = 0; s < 51; s++){
    __syncthreads();                   // previous compute's LDS reads done
    #pragma unroll
    for (int it=0; it<8; it++){
      int u = tid + it*256;
      int a = (u>>5)*MSTR + (u&31);
      ushort h0,h1,h2; split3(stgx[it], h0,h1,h2);
      xpl[a] = h0; xpl[2560 + a] = h1; xpl[5120 + a] = h2;
    }
    #pragma unroll
    for (int i=0; i<6; i++)
      *(uint4*)&wch[i*2560 + wdst] = stgw[i];
    __syncthreads();                   // staged data visible
    if (s+1 < 51){
      const int k0n = (s+1)*32;
      #pragma unroll
      for (int it=0; it<8; it++){
        int u = tid + it*256;
        int kg = k0n + (u&31);
        stgx[it] = (kg < NC) ? x[(size_t)(row0 + (u>>5))*NC + kg] : 0.f;
      }
      #pragma unroll
      for (int i=0; i<6; i++)
        stgw[i] = *(const uint4*)(w1s + (size_t)(i*51 + s+1)*2048 + tid*8);
    }
    short8 Af[3];
    #pragma unroll
    for (int p=0; p<3; p++)
      Af[p] = *(const short8*)&xpl[p*2560 + (wave*16 + col)*MSTR + quad*8];
    #pragma unroll
    for (int h=0; h<2; h++)
      #pragma unroll
      for (int nt=0; nt<4; nt++){
        short8 B0 = *(const short8*)&wch[(h*3+0)*2560 + nt*640 + col*40 + quad*8];
        short8 B1 = *(const short8*)&wch[(h*3+1)*2560 + nt*640 + col*40 + quad*8];
        short8 B2 = *(const short8*)&wch[(h*3+2)*2560 + nt*640 + col*40 + quad*8];
        MFMA6(acc[h][nt], Af[0],Af[1],Af[2], B0,B1,B2);
      }
  }
  __syncthreads();   // wch reused as h-planes

  ushort* hp = wch;  // [p][row*HSTR + d], p stride 64*HSTR=4608 (13824 <= 15360)
  #pragma unroll 1
  for (int h=0; h<2; h++){
    const float* b1 = h ? bo1 : bs1;
    const float* b2 = h ? bo2 : bs2;
    ushort* pl = h ? oPl : sPl;
    #pragma unroll
    for (int nt=0; nt<4; nt++){
      float bias = b1[nt*16 + col];
      #pragma unroll
      for (int r=0; r<4; r++){
        float hv = fmaxf(acc[h][nt][r] + bias, 0.f);
        ushort h0,h1,h2; split3(hv,h0,h1,h2);
        int a = (wave*16 + quad*4 + r)*HSTR + nt*16 + col;
        hp[a] = h0; hp[4608 + a] = h1; hp[2*4608 + a] = h2;
      }
    }
    __syncthreads();
    floatx4 acc2[4];
    #pragma unroll
    for (int nt=0; nt<4; nt++) acc2[nt] = (floatx4){0.f,0.f,0.f,0.f};
    #pragma unroll
    for (int t=0; t<2; t++){
      short8 Af2[3];
      #pragma unroll
      for (int p=0; p<3; p++)
        Af2[p] = *(const short8*)&hp[p*4608 + (wave*16 + col)*HSTR + t*32 + quad*8];
      #pragma unroll
      for (int nt=0; nt<4; nt++){
        short8 Bq0 = *(const short8*)(w2s + (size_t)(((h*3+0)*2 + t)*2048 + nt*512 + col*32 + quad*8));
        short8 Bq1 = *(const short8*)(w2s + (size_t)(((h*3+1)*2 + t)*2048 + nt*512 + col*32 + quad*8));
        short8 Bq2 = *(const short8*)(w2s + (size_t)(((h*3+2)*2 + t)*2048 + nt*512 + col*32 + quad*8));
        MFMA6(acc2[nt], Af2[0],Af2[1],Af2[2], Bq0,Bq1,Bq2);
      }
    }
    #pragma unroll
    for (int nt=0; nt<4; nt++){
      float bv = b2[nt*16 + col];
      #pragma unroll
      for (int r=0; r<4; r++){
        int gr = row0 + wave*16 + quad*4 + r;
        float yv = acc2[nt][r] + bv;
        ushort h0,h1,h2; split3(yv,h0,h1,h2);
        size_t base = (size_t)gr*64 + nt*16 + col;
        pl[base] = h0; pl[PLSZ + base] = h1; pl[2*PLSZ + base] = h2;
      }
    }
    __syncthreads();   // hp reuse between heads
  }
}

// ---------------------------------------------------------------------------
// Shared MFMA tile for pass1/pass2: 128x128 scores, K=64 in two 32-halves,
// fragments direct from global bf16 planes. Identical streams in both passes
// -> bitwise-consistent keys (no margins needed anywhere).
// ---------------------------------------------------------------------------
__device__ __forceinline__ void score_tile_mfma(
    const ushort* __restrict__ sPl, const ushort* __restrict__ oPl,
    int b, int ti, int tj, int lane, int wave,
    floatx4 (&acc)[2][8])
{
  const int col  = lane & 15;
  const int quad = lane >> 4;
  #pragma unroll
  for (int mt=0; mt<2; mt++)
    #pragma unroll
    for (int nt=0; nt<8; nt++) acc[mt][nt] = (floatx4){0.f,0.f,0.f,0.f};

  #pragma unroll
  for (int half=0; half<2; half++){
    short8 Af[2][3];
    #pragma unroll
    for (int mt=0; mt<2; mt++){
      int row = b*NN + ti + wave*32 + mt*16 + col;
      row = row < ROWS ? row : (ROWS-1);
      #pragma unroll
      for (int p=0; p<3; p++)
        Af[mt][p] = *(const short8*)&sPl[(size_t)p*PLSZ + (size_t)row*64 + half*32 + quad*8];
    }
    #pragma unroll
    for (int nt=0; nt<8; nt++){
      int row2 = b*NN + tj + nt*16 + col;
      row2 = row2 < ROWS ? row2 : (ROWS-1);
      short8 Bf[3];
      #pragma unroll
      for (int p=0; p<3; p++)
        Bf[p] = *(const short8*)&oPl[(size_t)p*PLSZ + (size_t)row2*64 + half*32 + quad*8];
      #pragma unroll
      for (int mt=0; mt<2; mt++)
        MFMA6(acc[mt][nt], Af[mt][0],Af[mt][1],Af[mt][2], Bf[0],Bf[1],Bf[2]);
    }
  }
}

// ---------------------------------------------------------------------------
// Pass 1: complete 12-bit key histogram of ALL scores (LDS hist, sparse
// global flush). No candidates, no thresholds, no sampling.
// ---------------------------------------------------------------------------
__global__ __launch_bounds__(256) void score_hist(
    const ushort* __restrict__ sPl, const ushort* __restrict__ oPl,
    uint32_t* __restrict__ ghist)
{
  __shared__ uint32_t hist[NBIN];     // 16 KB
  const int blk = blockIdx.x;
  const int b   = blk >> 6;
  const int t   = blk & 63;
  const int ti  = (t >> 3) << 7;
  const int tj  = (t & 7)  << 7;
  const int tid = threadIdx.x;
  const int lane = tid & 63, wave = tid >> 6;
  const int col = lane & 15, quad = lane >> 4;

  for (int i = tid; i < NBIN; i += 256) hist[i] = 0;
  __syncthreads();

  floatx4 acc[2][8];
  score_tile_mfma(sPl, oPl, b, ti, tj, lane, wave, acc);

  #pragma unroll
  for (int mt=0; mt<2; mt++)
    #pragma unroll
    for (int nt=0; nt<8; nt++)
      #pragma unroll
      for (int r=0; r<4; r++){
        int gi = ti + wave*32 + mt*16 + quad*4 + r;
        int gj = tj + nt*16 + col;
        if (gi < NN && gj < NN)
          atomicAdd(&hist[f2key(acc[mt][nt][r]) >> 20], 1u);
      }
  __syncthreads();
  for (int i = tid; i < NBIN; i += 256){
    uint32_t v = hist[i];
    if (v) atomicAdd(&ghist[(size_t)b*NBIN + i], v);
  }
}

// ---------------------------------------------------------------------------
// Pick: exact 12-bit bucket floor T[b] of the 64th-largest key (full hist).
// ---------------------------------------------------------------------------
__global__ __launch_bounds__(256, 1) void pick_thresh(
    const uint32_t* __restrict__ ghist, uint32_t* __restrict__ T)
{
  __shared__ uint32_t S[256];
  const int b = blockIdx.x, tid = threadIdx.x;
  const uint32_t* h = ghist + (size_t)b*NBIN;
  uint32_t loc[16];
  uint32_t s = 0;
  #pragma unroll
  for (int i=0;i<16;i++){ loc[i] = h[tid*16 + i]; s += loc[i]; }
  S[tid] = s;
  __syncthreads();
  for (int off = 1; off < 256; off <<= 1){
    uint32_t v = (tid + off < 256) ? S[tid + off] : 0u;
    __syncthreads();
    S[tid] += v;
    __syncthreads();
  }
  uint32_t above = (tid < 255) ? S[tid + 1] : 0u;
  if (above < 64u && S[tid] >= 64u){
    uint32_t suf = above; int best = 0;
    for (int i=15;i>=0;i--){ suf += loc[i]; if (suf >= 64u){ best = i; break; } }
    T[b] = (uint32_t)(tid*16 + best) << 20;
  }
}

// ---------------------------------------------------------------------------
// Pass 2: recompute scores (identical stream), append keys >= T[b] into cand
// (expected ~100-300 per batch) via two-phase reservation.
// ---------------------------------------------------------------------------
__global__ __launch_bounds__(256) void select_cand(
    const ushort* __restrict__ sPl, const ushort* __restrict__ oPl,
    const uint32_t* __restrict__ T, uint32_t* __restrict__ cntW,
    uint2* __restrict__ cand)
{
  __shared__ uint32_t lcnt, gbase;
  const int blk = blockIdx.x;
  const int b   = blk >> 6;
  const int t   = blk & 63;
  const int ti  = (t >> 3) << 7;
  const int tj  = (t & 7)  << 7;
  const int tid = threadIdx.x;
  const int lane = tid & 63, wave = tid >> 6;
  const int col = lane & 15, quad = lane >> 4;

  if (tid == 0) lcnt = 0;
  __syncthreads();

  floatx4 acc[2][8];
  score_tile_mfma(sPl, oPl, b, ti, tj, lane, wave, acc);

  const uint32_t Tb = T[b];
  int myCnt = 0;
  #pragma unroll
  for (int mt=0; mt<2; mt++)
    #pragma unroll
    for (int nt=0; nt<8; nt++)
      #pragma unroll
      for (int r=0; r<4; r++){
        int gi = ti + wave*32 + mt*16 + quad*4 + r;
        int gj = tj + nt*16 + col;
        if (gi < NN && gj < NN && f2key(acc[mt][nt][r]) >= Tb) myCnt++;
      }
  uint32_t lbase = atomicAdd(&lcnt, (uint32_t)myCnt);
  __syncthreads();
  if (tid == 0) gbase = atomicAdd(&cntW[b], lcnt);
  __syncthreads();
  uint32_t pos = gbase + lbase;
  #pragma unroll
  for (int mt=0; mt<2; mt++)
    #pragma unroll
    for (int nt=0; nt<8; nt++)
      #pragma unroll
      for (int r=0; r<4; r++){
        int gi = ti + wave*32 + mt*16 + quad*4 + r;
        int gj = tj + nt*16 + col;
        if (gi < NN && gj < NN){
          uint32_t key = f2key(acc[mt][nt][r]);
          if (key >= Tb){
            if (pos < CAPB) cand[(size_t)b*CAPB + pos] = make_uint2(key, (uint32_t)(gi*NN + gj));
            pos++;
          }
        }
      }
}

// ---------------------------------------------------------------------------
// Final: exact top-64 per batch from the small candidate list. Radix-select
// the 64th key, rank by (value desc, index asc) = jax.lax.top_k ties.
// ---------------------------------------------------------------------------
__global__ __launch_bounds__(256, 1) void final_select(
    const uint32_t* __restrict__ cntW, const uint2* __restrict__ cand,
    float* __restrict__ out)
{
  __shared__ uint32_t keys[CAPB];     // 16 KB
  __shared__ uint32_t hist[256];
  __shared__ uint32_t sb[2];
  __shared__ uint2 win[192];
  __shared__ uint32_t wn;
  const int b = blockIdx.x, tid = threadIdx.x;
  uint32_t n0 = cntW[b];
  const int n = (n0 < (uint32_t)CAPB) ? (int)n0 : CAPB;

  for (int i = tid; i < n; i += 256) keys[i] = cand[(size_t)b*CAPB + i].x;
  if (tid == 0) wn = 0;
  __syncthreads();

  uint32_t prefix = 0; int remaining = 64;
  for (int round = 0; round < 4; round++){
    const int shift = 24 - round*8;
    hist[tid] = 0;
    __syncthreads();
    for (int i = tid; i < n; i += 256){
      uint32_t k = keys[i];
      bool match = (round == 0) || ((k >> (shift+8)) == (prefix >> (shift+8)));
      if (match) atomicAdd(&hist[(k >> shift) & 255u], 1u);
    }
    __syncthreads();
    if (tid == 0){
      uint32_t cum = 0; int bin = 255;
      for (;; bin--){ cum += hist[bin]; if (cum >= (uint32_t)remaining || bin == 0) break; }
      sb[0] = (uint32_t)bin;
      sb[1] = (uint32_t)(remaining - (int)(cum - hist[bin]));
    }
    __syncthreads();
    prefix |= sb[0] << shift;
    remaining = (int)sb[1];
    __syncthreads();
  }
  const uint32_t Tk = prefix;

  for (int i = tid; i < n; i += 256){
    if (keys[i] >= Tk){
      uint32_t p = atomicAdd(&wn, 1u);
      if (p < 192u) win[p] = make_uint2(keys[i], cand[(size_t)b*CAPB + i].y);
    }
  }
  __syncthreads();
  const int m = (wn < 192u) ? (int)wn : 192;

  if (tid < m){
    const uint64_t me = ((uint64_t)win[tid].x << 32) | (uint64_t)(uint32_t)(~win[tid].y);
    int rank = 0;
    for (int s = 0; s < m; s++){
      uint64_t oth = ((uint64_t)win[s].x << 32) | (uint64_t)(uint32_t)(~win[s].y);
      rank += (oth > me) ? 1 : 0;
    }
    if (rank < 64){
      const uint32_t f = win[tid].y;
      const float d  = key2f(win[tid].x);
      const float sc = 1.0f / (1.0f + expf(-d));
      out[((size_t)b*64 + rank)*2 + 0] = (float)(f / NN);
      out[((size_t)b*64 + rank)*2 + 1] = (float)(f % NN);
      out[(size_t)NB*64*2 + (size_t)b*64 + rank] = sc;
    }
  }
}

// ---------------------------------------------------------------------------
extern "C" void kernel_launch(void* const* d_in, const int* in_sizes, int n_in,
                              void* d_out, int out_size, void* d_ws, size_t ws_size,
                              hipStream_t stream) {
  const float* x   = (const float*)d_in[0];
  const float* Ws1 = (const float*)d_in[2];
  const float* bs1 = (const float*)d_in[3];
  const float* Ws2 = (const float*)d_in[4];
  const float* bs2 = (const float*)d_in[5];
  const float* Wo1 = (const float*)d_in[6];
  const float* bo1 = (const float*)d_in[7];
  const float* Wo2 = (const float*)d_in[8];
  const float* bo2 = (const float*)d_in[9];
  float* out = (float*)d_out;

  char* ws = (char*)d_ws;
  ushort*   sPl  = (ushort*)  ws;                     // 12,288,000 B
  ushort*   oPl  = (ushort*)  (ws + 12288000);        // 12,288,000 B
  uint32_t* cntW = (uint32_t*)(ws + 24576000);        //        128 B
  uint32_t* ghist= (uint32_t*)(ws + 24576128);        //    524,288 B
  uint32_t* T    = (uint32_t*)(ws + 25100416);        //        128 B
  uint2*    cand = (uint2*)   (ws + 25100544);        //  1,048,576 B
  ushort*   w1s  = (ushort*)  (ws + 26149120);        //  1,253,376 B
  ushort*   w2s  = (ushort*)  (ws + 27402496);        //     49,152 B (~27.5 MB)

  hipMemsetAsync(cntW, 0, 128 + 524288, stream);      // cntW + ghist contiguous

  prep_w<<<848, 256, 0, stream>>>(Ws1, Wo1, Ws2, Wo2, w1s, w2s);
  mlp_mfma<<<ROWS/64, 256, 0, stream>>>(x, w1s, w2s, bs1, bs2, bo1, bo2, sPl, oPl);
  score_hist<<<NB*64, 256, 0, stream>>>(sPl, oPl, ghist);
  pick_thresh<<<NB, 256, 0, stream>>>(ghist, T);
  select_cand<<<NB*64, 256, 0, stream>>>(sPl, oPl, T, cntW, cand);
  final_select<<<NB, 256, 0, stream>>>(cntW, cand, out);
}